// Round 5
// baseline (4550.432 us; speedup 1.0000x reference)
//
#include <hip/hip_runtime.h>
#include <hip/hip_bf16.h>

// ---------- helpers ----------
__device__ __forceinline__ float bf2f(unsigned short u) {
    union { unsigned int i; float f; } v;
    v.i = ((unsigned int)u) << 16;
    return v.f;
}
__device__ __forceinline__ unsigned short f2bf(float f) {
    __hip_bfloat16 h = __float2bfloat16(f);   // RNE
    return *reinterpret_cast<unsigned short*>(&h);
}

// ---------- dtype probe: flag=0 -> bf16 inputs, flag=1 -> f32 inputs ----------
__global__ void probe_dtype(const unsigned short* __restrict__ x, int* flag) {
    if (blockIdx.x == 0 && threadIdx.x == 0) {
        int wild = 0;
        for (int i = 0; i < 512; ++i) {
            unsigned e = (x[i] >> 7) & 0xFF;
            if (e >= 0xC0) ++wild;
        }
        *flag = (wild > 0) ? 1 : 0;
    }
}

// ---------- histogram over 64-row buckets ----------
__global__ __launch_bounds__(256) void hist_kernel(
    const int* __restrict__ rows, int nnz, int* __restrict__ cnt)
{
    int e = blockIdx.x * 256 + threadIdx.x;
    if (e < nnz) atomicAdd(&cnt[rows[e] >> 6], 1);
}

// ---------- exclusive scan over nb <= 4096 buckets; init cursor = base ----------
__global__ __launch_bounds__(1024) void scan_kernel(
    const int* __restrict__ cnt, int* __restrict__ base,
    int* __restrict__ cursor, int nb)
{
    __shared__ int tmp[1024];
    const int t = threadIdx.x;
    int loc[4]; int s = 0;
#pragma unroll
    for (int j = 0; j < 4; ++j) {
        int idx = t * 4 + j; loc[j] = s;
        s += (idx < nb) ? cnt[idx] : 0;
    }
    tmp[t] = s; __syncthreads();
    for (int off = 1; off < 1024; off <<= 1) {
        int v = (t >= off) ? tmp[t - off] : 0;
        __syncthreads();
        tmp[t] += v;
        __syncthreads();
    }
    int pre = (t > 0) ? tmp[t - 1] : 0;
#pragma unroll
    for (int j = 0; j < 4; ++j) {
        int idx = t * 4 + j;
        if (idx < nb) { int b = pre + loc[j]; base[idx] = b; cursor[idx] = b; }
    }
    if (t == 1023) base[nb] = tmp[1023];
}

// ---------- permute edges into bucket-contiguous int4 records ----------
// pk = {col, val_f32_bits, row&63, 0}
__global__ __launch_bounds__(256) void permute_kernel(
    const int* __restrict__ rows, const int* __restrict__ cols,
    const void* __restrict__ vals, const int* __restrict__ flag,
    int* __restrict__ cursor, int4* __restrict__ packed, int nnz)
{
    int e = blockIdx.x * 256 + threadIdx.x;
    if (e >= nnz) return;
    int r = rows[e];
    int pos = atomicAdd(&cursor[r >> 6], 1);
    float v = (*flag) ? ((const float*)vals)[e]
                      : bf2f(((const unsigned short*)vals)[e]);
    int4 pk;
    pk.x = cols[e]; pk.y = __float_as_int(v); pk.z = r & 63; pk.w = 0;
    packed[pos] = pk;
}

// ---------- fused: LDS segment-sum (bucket of 64 rows) -> @W -> epilogue ----------
// mode 0: m[g] = relu(T * cci[g])   (overwrite)
// mode 1: m[g] += relu(T)           (accumulate)
__global__ __launch_bounds__(256) void reduce_gemm(
    const int4* __restrict__ packed, const int* __restrict__ base,
    const void* __restrict__ x,      // gather source (bf16 or f32 per flag)
    const void* __restrict__ W,      // 64x64
    const void* __restrict__ cci,    // rank cci base (mode 0 only)
    void* mout,                      // d_out base
    const int* __restrict__ flag,
    int N, long long mbase, int mode)
{
    __shared__ float accS[64][65];   // +1 pad: conflict-free GEMM row reads
    __shared__ float Ws[64][64];
    const int tid = threadIdx.x;
    const int fl = *flag;

    if (fl) {
        const float* Wf = (const float*)W;
        for (int i = tid; i < 4096; i += 256) Ws[i >> 6][i & 63] = Wf[i];
    } else {
        const unsigned short* Wb = (const unsigned short*)W;
        for (int i = tid; i < 4096; i += 256) Ws[i >> 6][i & 63] = bf2f(Wb[i]);
    }
    float* az = &accS[0][0];
    for (int i = tid; i < 64 * 65; i += 256) az[i] = 0.f;
    __syncthreads();

    const int bkt = blockIdx.x;
    const int start = base[bkt], end = base[bkt + 1];
    const int wave = tid >> 6, lane = tid & 63;

    if (fl) {
        const float* xf = (const float*)x;
        int e = start + wave;
        for (; e + 4 < end; e += 8) {
            int4 p0 = packed[e], p1 = packed[e + 4];
            float x0 = xf[(size_t)p0.x * 64 + lane];
            float x1 = xf[(size_t)p1.x * 64 + lane];
            atomicAdd(&accS[p0.z][lane], __int_as_float(p0.y) * x0);
            atomicAdd(&accS[p1.z][lane], __int_as_float(p1.y) * x1);
        }
        for (; e < end; e += 4) {
            int4 pk = packed[e];
            float xv = xf[(size_t)pk.x * 64 + lane];
            atomicAdd(&accS[pk.z][lane], __int_as_float(pk.y) * xv);
        }
    } else {
        const unsigned short* xb = (const unsigned short*)x;
        int e = start + wave;
        for (; e + 4 < end; e += 8) {          // 2-way unroll for MLP
            int4 p0 = packed[e], p1 = packed[e + 4];
            float x0 = bf2f(xb[(size_t)p0.x * 64 + lane]);
            float x1 = bf2f(xb[(size_t)p1.x * 64 + lane]);
            atomicAdd(&accS[p0.z][lane], __int_as_float(p0.y) * x0);
            atomicAdd(&accS[p1.z][lane], __int_as_float(p1.y) * x1);
        }
        for (; e < end; e += 4) {
            int4 pk = packed[e];
            float xv = bf2f(xb[(size_t)pk.x * 64 + lane]);
            atomicAdd(&accS[pk.z][lane], __int_as_float(pk.y) * xv);
        }
    }
    __syncthreads();

    // GEMM: T[64x64] = accS @ Ws ; thread (tx,ty): 4 rows x 4 cols
    const int tx = tid & 15, ty = tid >> 4;
    float a4[4][4];
#pragma unroll
    for (int a = 0; a < 4; ++a)
#pragma unroll
        for (int b = 0; b < 4; ++b) a4[a][b] = 0.f;

#pragma unroll 8
    for (int k = 0; k < 64; ++k) {
        float4 w4 = *reinterpret_cast<const float4*>(&Ws[k][tx << 2]);
#pragma unroll
        for (int rr = 0; rr < 4; ++rr) {
            float xv = accS[ty + 16 * rr][k];
            a4[rr][0] += xv * w4.x;
            a4[rr][1] += xv * w4.y;
            a4[rr][2] += xv * w4.z;
            a4[rr][3] += xv * w4.w;
        }
    }

    const int row0 = bkt * 64;
#pragma unroll
    for (int rr = 0; rr < 4; ++rr) {
        int g = row0 + ty + 16 * rr;
        if (g >= N) continue;
        size_t co = (size_t)g * 64 + (tx << 2);
        size_t ob = (size_t)mbase + co;
        float t[4] = { a4[rr][0], a4[rr][1], a4[rr][2], a4[rr][3] };
        if (mode == 0) {
            float c4[4];
            if (fl) {
                float4 cv = *reinterpret_cast<const float4*>(&((const float*)cci)[co]);
                c4[0] = cv.x; c4[1] = cv.y; c4[2] = cv.z; c4[3] = cv.w;
            } else {
                ushort4 cv = *reinterpret_cast<const ushort4*>(&((const unsigned short*)cci)[co]);
                c4[0] = bf2f(cv.x); c4[1] = bf2f(cv.y); c4[2] = bf2f(cv.z); c4[3] = bf2f(cv.w);
            }
#pragma unroll
            for (int j = 0; j < 4; ++j) t[j] = fmaxf(t[j] * c4[j], 0.f);
            if (fl) {
                float4 o; o.x = t[0]; o.y = t[1]; o.z = t[2]; o.w = t[3];
                *reinterpret_cast<float4*>(&((float*)mout)[ob]) = o;
            } else {
                ushort4 o; o.x = f2bf(t[0]); o.y = f2bf(t[1]); o.z = f2bf(t[2]); o.w = f2bf(t[3]);
                *reinterpret_cast<ushort4*>(&((unsigned short*)mout)[ob]) = o;
            }
        } else {
            if (fl) {
                float* mp = (float*)mout;
                float4 ov = *reinterpret_cast<const float4*>(&mp[ob]);
                float4 o;
                o.x = ov.x + fmaxf(t[0], 0.f);
                o.y = ov.y + fmaxf(t[1], 0.f);
                o.z = ov.z + fmaxf(t[2], 0.f);
                o.w = ov.w + fmaxf(t[3], 0.f);
                *reinterpret_cast<float4*>(&mp[ob]) = o;
            } else {
                unsigned short* mp = (unsigned short*)mout;
                ushort4 ov = *reinterpret_cast<const ushort4*>(&mp[ob]);
                ushort4 o;
                o.x = f2bf(bf2f(ov.x) + fmaxf(t[0], 0.f));
                o.y = f2bf(bf2f(ov.y) + fmaxf(t[1], 0.f));
                o.z = f2bf(bf2f(ov.z) + fmaxf(t[2], 0.f));
                o.w = f2bf(bf2f(ov.w) + fmaxf(t[3], 0.f));
                *reinterpret_cast<ushort4*>(&mp[ob]) = o;
            }
        }
    }
}

// ---------- finalize: out = relu(m @ Wg). m aliases out (LDS-staged) ----------
__global__ __launch_bounds__(256) void finalize(
    void* mout, const void* __restrict__ Wg, const int* __restrict__ flag,
    int N, long long mbase)
{
    __shared__ float Ws[64][64];
    __shared__ float ms[64][65];
    const int tid = threadIdx.x;
    const int tx = tid & 15, ty = tid >> 4;
    const int fl = *flag;

    if (fl) {
        const float* Wf = (const float*)Wg;
        for (int i = tid; i < 4096; i += 256) Ws[i >> 6][i & 63] = Wf[i];
    } else {
        const unsigned short* Wb = (const unsigned short*)Wg;
        for (int i = tid; i < 4096; i += 256) Ws[i >> 6][i & 63] = bf2f(Wb[i]);
    }
    const int row0 = blockIdx.x * 64;
    for (int i = tid; i < 4096; i += 256) {
        int r = i >> 6, c = i & 63;
        int g = row0 + r;
        float v = 0.f;
        if (g < N) {
            size_t o = (size_t)mbase + (size_t)g * 64 + c;
            v = fl ? ((const float*)mout)[o] : bf2f(((const unsigned short*)mout)[o]);
        }
        ms[r][c] = v;
    }
    __syncthreads();

    float a4[4][4];
#pragma unroll
    for (int a = 0; a < 4; ++a)
#pragma unroll
        for (int b = 0; b < 4; ++b) a4[a][b] = 0.f;

#pragma unroll 8
    for (int k = 0; k < 64; ++k) {
        float4 w4 = *reinterpret_cast<const float4*>(&Ws[k][tx << 2]);
#pragma unroll
        for (int rr = 0; rr < 4; ++rr) {
            float xv = ms[ty + 16 * rr][k];
            a4[rr][0] += xv * w4.x;
            a4[rr][1] += xv * w4.y;
            a4[rr][2] += xv * w4.z;
            a4[rr][3] += xv * w4.w;
        }
    }
#pragma unroll
    for (int rr = 0; rr < 4; ++rr) {
        int g = row0 + ty + 16 * rr;
        if (g >= N) continue;
        size_t ob = (size_t)mbase + (size_t)g * 64 + (tx << 2);
        if (fl) {
            float4 o;
            o.x = fmaxf(a4[rr][0], 0.f); o.y = fmaxf(a4[rr][1], 0.f);
            o.z = fmaxf(a4[rr][2], 0.f); o.w = fmaxf(a4[rr][3], 0.f);
            *reinterpret_cast<float4*>(&((float*)mout)[ob]) = o;
        } else {
            ushort4 o;
            o.x = f2bf(fmaxf(a4[rr][0], 0.f)); o.y = f2bf(fmaxf(a4[rr][1], 0.f));
            o.z = f2bf(fmaxf(a4[rr][2], 0.f)); o.w = f2bf(fmaxf(a4[rr][3], 0.f));
            *reinterpret_cast<ushort4*>(&((unsigned short*)mout)[ob]) = o;
        }
    }
}

extern "C" void kernel_launch(void* const* d_in, const int* in_sizes, int n_in,
                              void* d_out, int out_size, void* d_ws, size_t ws_size,
                              hipStream_t stream)
{
    static const int Ns[5] = {50000, 150000, 100000, 40000, 10000};

    // ---- input pointer map (setup_inputs dict order) ----
    const void *x[5], *av[5], *cci[5], *Whbs[5], *Wagg[5];
    const int *ar[5], *ac[5];
    int nnzA[5];
    for (int r = 0; r < 5; ++r) {
        x[r]    = d_in[r * 7 + 0];
        ar[r]   = (const int*)d_in[r * 7 + 1];
        ac[r]   = (const int*)d_in[r * 7 + 2];
        av[r]   = d_in[r * 7 + 3];
        cci[r]  = d_in[r * 7 + 4];
        Whbs[r] = d_in[r * 7 + 5];
        Wagg[r] = d_in[r * 7 + 6];
        nnzA[r] = in_sizes[r * 7 + 3];
    }
    const int *it[4], *is[4];
    const void *iv[4], *Wsp[4], *Wtp[4];
    int nnzI[4];
    for (int k = 0; k < 4; ++k) {
        it[k]  = (const int*)d_in[35 + k * 5 + 0];
        is[k]  = (const int*)d_in[35 + k * 5 + 1];
        iv[k]  = d_in[35 + k * 5 + 2];
        Wsp[k] = d_in[35 + k * 5 + 3];
        Wtp[k] = d_in[35 + k * 5 + 4];
        nnzI[k] = in_sizes[35 + k * 5 + 2];
    }

    // ---- workspace layout (~20 MB; ws_size known >= 38.4 MB from R4) ----
    char* ws = (char*)d_ws;
    int*  cnt    = (int*)(ws);                 // 4096 ints
    int*  base_  = (int*)(ws + 16384);         // 4097 ints
    int*  cursor = (int*)(ws + 36864);         // 4096 ints
    int4* packed = (int4*)(ws + 65536);        // nnz_max(1.2M) * 16 B = 19.2 MB
    size_t flag_off = (ws_size - 4) & ~(size_t)3;
    int* flag = (int*)(ws + flag_off);

    probe_dtype<<<1, 64, 0, stream>>>((const unsigned short*)x[0], flag);

    dim3 b256(256);
    long long mbase = 0;   // element offset of rank's block in d_out

    for (int r = 0; r < 5; ++r) {
        const int N = Ns[r];
        const int nb = (N + 63) >> 6;

        // phase table: {rows, cols, vals, xsrc, W, nnz, mode}
        struct Ph { const int* rw; const int* cl; const void* vl;
                    const void* xs; const void* W; int nnz; int mode; };
        Ph ph[3]; int np = 0;
        ph[np++] = { ar[r], ac[r], av[r], x[r], Whbs[r], nnzA[r], 0 };               // same-rank
        if (r < 4) ph[np++] = { it[r], is[r], iv[r], x[r + 1], Wsp[r], nnzI[r], 1 }; // down
        if (r > 0) ph[np++] = { is[r - 1], it[r - 1], iv[r - 1], x[r - 1], Wtp[r - 1],
                                nnzI[r - 1], 1 };                                     // up

        for (int p = 0; p < np; ++p) {
            const int nnz = ph[p].nnz;
            hipMemsetAsync(cnt, 0, (size_t)nb * 4, stream);
            hist_kernel<<<(nnz + 255) / 256, b256, 0, stream>>>(ph[p].rw, nnz, cnt);
            scan_kernel<<<1, 1024, 0, stream>>>(cnt, base_, cursor, nb);
            permute_kernel<<<(nnz + 255) / 256, b256, 0, stream>>>(
                ph[p].rw, ph[p].cl, ph[p].vl, flag, cursor, packed, nnz);
            reduce_gemm<<<nb, b256, 0, stream>>>(
                packed, base_, ph[p].xs, ph[p].W, cci[r], d_out, flag,
                N, mbase, ph[p].mode);
        }
        finalize<<<(N + 63) / 64, b256, 0, stream>>>(d_out, Wagg[r], flag, N, mbase);
        mbase += (long long)N * 64;
    }
}